// Round 7
// baseline (305.406 us; speedup 1.0000x reference)
//
#include <hip/hip_runtime.h>
#include <cstddef>
#include <cstdint>

#define S_LEN 2048
#define NHEAD 16
#define HDIM  64
#define EMB   1024
#define MROWS 4096

typedef short bf16x8 __attribute__((ext_vector_type(8)));
typedef float f32x4 __attribute__((ext_vector_type(4)));

// round-to-nearest fp32->bf16: 2 VALU ops
__device__ __forceinline__ unsigned short f2bf(float f) {
  union { float f; unsigned u; } v; v.f = f;
  return (unsigned short)((v.u + 0x8000u) >> 16);
}
__device__ __forceinline__ unsigned pack2bf(float a, float b) {
  union { float f; unsigned u; } x, y; x.f = a; y.f = b;
  return ((x.u + 0x8000u) >> 16) | ((y.u + 0x8000u) & 0xFFFF0000u);
}

__device__ __forceinline__ f32x4 fzero() {
  f32x4 z = {0.0f, 0.0f, 0.0f, 0.0f};
  return z;
}

// Cast x (4M), Wq,Wk,Wv,Wfc (1M each) fp32 -> bf16, contiguous dst.
__global__ __launch_bounds__(256) void cast_kernel(
    const float* __restrict__ x, const float* __restrict__ Wq,
    const float* __restrict__ Wk, const float* __restrict__ Wv,
    const float* __restrict__ Wfc, unsigned short* __restrict__ dst)
{
  size_t idx8 = (size_t)(blockIdx.x * 256 + threadIdx.x) * 8;
  unsigned seg = (unsigned)(idx8 >> 20);
  const float* src;
  size_t off;
  if (seg < 4) { src = x; off = idx8; }
  else {
    const float* w4[4] = {Wq, Wk, Wv, Wfc};
    src = w4[seg - 4];
    off = idx8 & 0xFFFFFu;
  }
  float4 a = *(const float4*)&src[off];
  float4 b = *(const float4*)&src[off + 4];
  uint4 p;
  p.x = pack2bf(a.x, a.y);
  p.y = pack2bf(a.z, a.w);
  p.z = pack2bf(b.x, b.y);
  p.w = pack2bf(b.z, b.w);
  *(uint4*)&dst[idx8] = p;
}

// QKV fused (R5 register-prefetch structure). z selects weight/bias/output.
// z=0: Qhd [bh][s][d]; z=1: Khd [bh][s][d] + KTd [bh][d][s]; z=2: VTd [bh][d][s].
__global__ __launch_bounds__(256) void gemm_qkv(
    const unsigned short* __restrict__ A, const unsigned short* __restrict__ Wall,
    const float* __restrict__ bq, const float* __restrict__ bk,
    const float* __restrict__ bv, unsigned short* __restrict__ Qhd,
    unsigned short* __restrict__ Khd, unsigned short* __restrict__ KTd,
    unsigned short* __restrict__ VTd)
{
  __shared__ short As[128][40];
  __shared__ short Bs[128][40];
  const int z = blockIdx.z;
  const unsigned short* B = Wall + (size_t)z * 1048576;
  const float* bias = (z == 0) ? bq : (z == 1) ? bk : bv;
  unsigned short* Yh = (z == 0) ? Qhd : (z == 1) ? Khd : nullptr;
  unsigned short* Yt = (z == 1) ? KTd : (z == 2) ? VTd : nullptr;
  const int K = EMB;
  const int t = threadIdx.x;
  const int lane = t & 63, w = t >> 6;
  const int quad = lane >> 4, l16 = lane & 15;
  const int wr = w >> 1, wc = w & 1;
  const int m0 = blockIdx.y * 128, n0 = blockIdx.x * 128;
  const int sr = t >> 2, sk = (t & 3) * 8;

  f32x4 acc[4][4];
#pragma unroll
  for (int i = 0; i < 4; ++i)
#pragma unroll
    for (int j = 0; j < 4; ++j) acc[i][j] = fzero();

  float4 pa0 = *(const float4*)&A[(size_t)(m0 + sr) * K + sk];
  float4 pa1 = *(const float4*)&A[(size_t)(m0 + 64 + sr) * K + sk];
  float4 pb0 = *(const float4*)&B[(size_t)(n0 + sr) * K + sk];
  float4 pb1 = *(const float4*)&B[(size_t)(n0 + 64 + sr) * K + sk];

  for (int k0 = 0; k0 < K; k0 += 32) {
    __syncthreads();
    *(float4*)&As[sr][sk] = pa0;
    *(float4*)&As[64 + sr][sk] = pa1;
    *(float4*)&Bs[sr][sk] = pb0;
    *(float4*)&Bs[64 + sr][sk] = pb1;
    __syncthreads();
    if (k0 + 32 < K) {
      pa0 = *(const float4*)&A[(size_t)(m0 + sr) * K + k0 + 32 + sk];
      pa1 = *(const float4*)&A[(size_t)(m0 + 64 + sr) * K + k0 + 32 + sk];
      pb0 = *(const float4*)&B[(size_t)(n0 + sr) * K + k0 + 32 + sk];
      pb1 = *(const float4*)&B[(size_t)(n0 + 64 + sr) * K + k0 + 32 + sk];
    }
    bf16x8 af[4], bfr[4];
#pragma unroll
    for (int i = 0; i < 4; ++i)
      af[i] = *(const bf16x8*)&As[64 * wr + 16 * i + l16][quad * 8];
#pragma unroll
    for (int j = 0; j < 4; ++j)
      bfr[j] = *(const bf16x8*)&Bs[64 * wc + 16 * j + l16][quad * 8];
#pragma unroll
    for (int i = 0; i < 4; ++i)
#pragma unroll
      for (int j = 0; j < 4; ++j)
        acc[i][j] = __builtin_amdgcn_mfma_f32_16x16x32_bf16(af[i], bfr[j], acc[i][j], 0, 0, 0);
  }

#pragma unroll
  for (int i = 0; i < 4; ++i) {
    int mb = m0 + 64 * wr + 16 * i + quad * 4;
#pragma unroll
    for (int j = 0; j < 4; ++j) {
      int n = n0 + 64 * wc + 16 * j + l16;
      float bvv = bias[n];
      int h = n >> 6, d = n & 63;
      if (Yh) {
#pragma unroll
        for (int r = 0; r < 4; ++r) {
          int m = mb + r;
          int b = m >> 11, s = m & 2047;
          Yh[((size_t)(b * NHEAD + h)) * 131072 + (size_t)s * 64 + d] =
              f2bf(acc[i][j][r] + bvv);
        }
      }
      if (Yt) {
        int b = mb >> 11, s = mb & 2047;
        uint2 pk;
        pk.x = pack2bf(acc[i][j][0] + bvv, acc[i][j][1] + bvv);
        pk.y = pack2bf(acc[i][j][2] + bvv, acc[i][j][3] + bvv);
        *(uint2*)&Yt[((size_t)(b * NHEAD + h)) * 131072 + (size_t)d * S_LEN + s] = pk;
      }
    }
  }
}

// Final: out = AO @ Wfc^T + bfc, fp32 out [M][N]. 128x64 tiles -> 512 blocks.
__global__ __launch_bounds__(256) void gemm_fc(
    const unsigned short* __restrict__ A, const unsigned short* __restrict__ B,
    const float* __restrict__ bias, float* __restrict__ Yf)
{
  __shared__ short As[128][40];
  __shared__ short Bs[64][40];
  const int K = EMB, N = EMB;
  const int t = threadIdx.x;
  const int lane = t & 63, w = t >> 6;
  const int quad = lane >> 4, l16 = lane & 15;
  const int wr = w >> 1, wc = w & 1;
  const int m0 = blockIdx.y * 128, n0 = blockIdx.x * 64;
  const int sr = t >> 2, sk = (t & 3) * 8;

  f32x4 acc[4][2];
#pragma unroll
  for (int i = 0; i < 4; ++i)
#pragma unroll
    for (int j = 0; j < 2; ++j) acc[i][j] = fzero();

  float4 pa0 = *(const float4*)&A[(size_t)(m0 + sr) * K + sk];
  float4 pa1 = *(const float4*)&A[(size_t)(m0 + 64 + sr) * K + sk];
  float4 pb0 = *(const float4*)&B[(size_t)(n0 + sr) * K + sk];

  for (int k0 = 0; k0 < K; k0 += 32) {
    __syncthreads();
    *(float4*)&As[sr][sk] = pa0;
    *(float4*)&As[64 + sr][sk] = pa1;
    if (sr < 64) *(float4*)&Bs[sr][sk] = pb0;
    __syncthreads();
    if (k0 + 32 < K) {
      pa0 = *(const float4*)&A[(size_t)(m0 + sr) * K + k0 + 32 + sk];
      pa1 = *(const float4*)&A[(size_t)(m0 + 64 + sr) * K + k0 + 32 + sk];
      pb0 = *(const float4*)&B[(size_t)(n0 + sr) * K + k0 + 32 + sk];
    }
    bf16x8 af[4], bfr[2];
#pragma unroll
    for (int i = 0; i < 4; ++i)
      af[i] = *(const bf16x8*)&As[64 * wr + 16 * i + l16][quad * 8];
#pragma unroll
    for (int j = 0; j < 2; ++j)
      bfr[j] = *(const bf16x8*)&Bs[32 * wc + 16 * j + l16][quad * 8];
#pragma unroll
    for (int i = 0; i < 4; ++i)
#pragma unroll
      for (int j = 0; j < 2; ++j)
        acc[i][j] = __builtin_amdgcn_mfma_f32_16x16x32_bf16(af[i], bfr[j], acc[i][j], 0, 0, 0);
  }

#pragma unroll
  for (int i = 0; i < 4; ++i) {
    int mb = m0 + 64 * wr + 16 * i + quad * 4;
#pragma unroll
    for (int j = 0; j < 2; ++j) {
      int n = n0 + 32 * wc + 16 * j + l16;
      float bvv = bias[n];
#pragma unroll
      for (int r = 0; r < 4; ++r)
        Yf[(size_t)(mb + r) * N + n] = acc[i][j][r] + bvv;
    }
  }
}

// Merged gram + Gauss-Jordan inverse. One block per (b,h).
// gram = K^T K via MFMA from KTd [bh][d][s]; GJ in LDS; bf16 ginv out.
__global__ __launch_bounds__(256) void graminv_kernel(
    const unsigned short* __restrict__ KTh, unsigned short* __restrict__ ginv)
{
  __shared__ short KTs[64][136];
  __shared__ float As[64][68];
  __shared__ float prow[2][64];
  __shared__ float fcol[2][64];
  const int t = threadIdx.x;
  const int lane = t & 63, w = t >> 6;
  const int quad = lane >> 4, l16 = lane & 15;
  const int bh = blockIdx.x;
  const unsigned short* Kb = KTh + (size_t)bh * 131072;

  // ---- gram via MFMA, 16 chunks of 128 sequence ----
  f32x4 gacc[4];
#pragma unroll
  for (int j = 0; j < 4; ++j) gacc[j] = fzero();
  const int rv = t >> 4, cv = (t & 15) * 8;
  for (int st = 0; st < 16; ++st) {
    float4 vv[4];
#pragma unroll
    for (int r = 0; r < 4; ++r)
      vv[r] = *(const float4*)&Kb[(size_t)(rv + 16 * r) * S_LEN + st * 128 + cv];
    __syncthreads();
#pragma unroll
    for (int r = 0; r < 4; ++r)
      *(float4*)&KTs[rv + 16 * r][cv] = vv[r];
    __syncthreads();
#pragma unroll
    for (int c = 0; c < 4; ++c) {
      bf16x8 ai = *(const bf16x8*)&KTs[16 * w + l16][32 * c + quad * 8];
#pragma unroll
      for (int jb = 0; jb < 4; ++jb) {
        bf16x8 bj = *(const bf16x8*)&KTs[16 * jb + l16][32 * c + quad * 8];
        gacc[jb] = __builtin_amdgcn_mfma_f32_16x16x32_bf16(ai, bj, gacc[jb], 0, 0, 0);
      }
    }
  }
  // dump to GJ working array (fp32)
#pragma unroll
  for (int jb = 0; jb < 4; ++jb)
#pragma unroll
    for (int r = 0; r < 4; ++r)
      As[16 * w + 4 * quad + r][16 * jb + l16] = gacc[jb][r];
  __syncthreads();

  // ---- Gauss-Jordan, in place, no pivoting (SPD diag-dominant) ----
  const int r = t >> 2;
  const int c0 = (t & 3) * 16;
  if (c0 == 0) fcol[0][r] = As[r][0];
  if (r == 0) {
#pragma unroll
    for (int jj = 0; jj < 4; ++jj)
      *(float4*)&prow[0][c0 + 4 * jj] = *(const float4*)&As[0][c0 + 4 * jj];
  }
  __syncthreads();

  for (int k = 0; k < 64; ++k) {
    const int kb = k & 1;
    const float f = fcol[kb][r];
    const float ip = 1.0f / fcol[kb][k];
    const float fi = f * ip;
    const bool pr = (r == k);
    float4 nv[4];
#pragma unroll
    for (int jj = 0; jj < 4; ++jj) {
      float4 a = *(const float4*)&As[r][c0 + 4 * jj];
      float4 p = *(const float4*)&prow[kb][c0 + 4 * jj];
      float4 o;
      if (pr) {
        o.x = p.x * ip; o.y = p.y * ip; o.z = p.z * ip; o.w = p.w * ip;
      } else {
        o.x = fmaf(-fi, p.x, a.x); o.y = fmaf(-fi, p.y, a.y);
        o.z = fmaf(-fi, p.z, a.z); o.w = fmaf(-fi, p.w, a.w);
      }
      const int cb = c0 + 4 * jj;
      const float kv = pr ? ip : -fi;
      if (cb == k) o.x = kv;
      if (cb + 1 == k) o.y = kv;
      if (cb + 2 == k) o.z = kv;
      if (cb + 3 == k) o.w = kv;
      *(float4*)&As[r][c0 + 4 * jj] = o;
      nv[jj] = o;
    }
    if (k < 63) {
      const int nk = k + 1, nb = nk & 1;
      if (nk >= c0 && nk < c0 + 16) fcol[nb][r] = As[r][nk];
      if (r == nk) {
#pragma unroll
        for (int jj = 0; jj < 4; ++jj) *(float4*)&prow[nb][c0 + 4 * jj] = nv[jj];
      }
    }
    __syncthreads();
  }

  unsigned short* O = ginv + (size_t)bh * 4096;
#pragma unroll
  for (int jj = 0; jj < 4; ++jj) {
    float4 v = *(const float4*)&As[r][c0 + 4 * jj];
    uint2 pk;
    pk.x = pack2bf(v.x, v.y);
    pk.y = pack2bf(v.z, v.w);
    *(uint2*)&O[r * 64 + c0 + 4 * jj] = pk;
  }
}

// Fused flash, 128-key iterations (two 64-key halves between barriers):
//  exp(half A) co-issues with S-MFMA(half B); K/V A-frags direct from global;
//  Qp B-frags reloaded from LDS per iter (VGPR control); exp2 with folded scale;
//  XCD swizzle keeps each bh's K/V resident in one XCD's L2.
__global__ __launch_bounds__(256, 4) void flash_mfma(
    const unsigned short* __restrict__ Qh, const unsigned short* __restrict__ Kh,
    const unsigned short* __restrict__ VTh, const unsigned short* __restrict__ Ginv,
    unsigned short* __restrict__ AO)
{
  __shared__ short Qps[64 * 72];     // [q][d], stride 72
  __shared__ short Ps[64 * 136];     // [q][128 keys], stride 136
  __shared__ float Lred[4][64];
  const int t = threadIdx.x;
  const int lane = t & 63, w = t >> 6;
  const int quad = lane >> 4, l16 = lane & 15;
  const int id = blockIdx.x;
  const int qt = (id >> 3) & 31;
  const int bh = ((id >> 8) << 3) | (id & 7);
  const unsigned short* Qb = Qh + (size_t)bh * 131072;
  const unsigned short* Kb = Kh + (size_t)bh * 131072;
  const unsigned short* Vb = VTh + (size_t)bh * 131072;
  const unsigned short* Gb = Ginv + (size_t)bh * 4096;

  // ---- phase 0: Qp = (Q @ Ginv) * log2(e)/32 -> Qps ----
  {
    bf16x8 aq[2];
#pragma unroll
    for (int c = 0; c < 2; ++c)
      aq[c] = *(const bf16x8*)&Qb[(size_t)(qt * 64 + 16 * w + l16) * 64 + 32 * c + 8 * quad];
    f32x4 qacc[4];
#pragma unroll
    for (int nb = 0; nb < 4; ++nb) qacc[nb] = fzero();
#pragma unroll
    for (int c = 0; c < 2; ++c) {
#pragma unroll
      for (int nb = 0; nb < 4; ++nb) {
        bf16x8 bg = *(const bf16x8*)&Gb[(size_t)(16 * nb + l16) * 64 + 32 * c + 8 * quad];
        qacc[nb] = __builtin_amdgcn_mfma_f32_16x16x32_bf16(aq[c], bg, qacc[nb], 0, 0, 0);
      }
    }
    const float cs = 0.04508422e0f;  // log2(e)/32
#pragma unroll
    for (int nb = 0; nb < 4; ++nb)
#pragma unroll
      for (int r = 0; r < 4; ++r)
        Qps[(16 * w + 4 * quad + r) * 72 + 16 * nb + l16] =
            (short)f2bf(qacc[nb][r] * cs);
  }
  __syncthreads();

  f32x4 oacc[4];
#pragma unroll
  for (int qb = 0; qb < 4; ++qb) oacc[qb] = fzero();
  float lsum[4] = {0.0f, 0.0f, 0.0f, 0.0f};

  for (int kt = 0; kt < 16; ++kt) {
    // K/V frags for this 128-key tile, issued up front
    bf16x8 ak0[2], ak1[2], av[4];
#pragma unroll
    for (int c = 0; c < 2; ++c)
      ak0[c] = *(const bf16x8*)&Kb[(size_t)(kt * 128 + 16 * w + l16) * 64 + 32 * c + 8 * quad];
#pragma unroll
    for (int c = 0; c < 2; ++c)
      ak1[c] = *(const bf16x8*)&Kb[(size_t)(kt * 128 + 64 + 16 * w + l16) * 64 + 32 * c + 8 * quad];
#pragma unroll
    for (int c = 0; c < 4; ++c)
      av[c] = *(const bf16x8*)&Vb[(size_t)(16 * w + l16) * S_LEN + kt * 128 + 32 * c + 8 * quad];

    // Qp B-frags from LDS (per-iter reload keeps VGPR pressure down)
    bf16x8 bqf[2][4];
#pragma unroll
    for (int c = 0; c < 2; ++c)
#pragma unroll
      for (int qb = 0; qb < 4; ++qb)
        bqf[c][qb] = *(const bf16x8*)&Qps[(16 * qb + l16) * 72 + 32 * c + 8 * quad];

    // S^T halves A and B (keys 16w.. / 64+16w..)
    f32x4 sa[4], sb[4];
#pragma unroll
    for (int qb = 0; qb < 4; ++qb) { sa[qb] = fzero(); sb[qb] = fzero(); }
#pragma unroll
    for (int c = 0; c < 2; ++c)
#pragma unroll
      for (int qb = 0; qb < 4; ++qb)
        sa[qb] = __builtin_amdgcn_mfma_f32_16x16x32_bf16(ak0[c], bqf[c][qb], sa[qb], 0, 0, 0);
#pragma unroll
    for (int c = 0; c < 2; ++c)
#pragma unroll
      for (int qb = 0; qb < 4; ++qb)
        sb[qb] = __builtin_amdgcn_mfma_f32_16x16x32_bf16(ak1[c], bqf[c][qb], sb[qb], 0, 0, 0);

    // P = 2^S for both halves -> Ps (exp(A) overlaps S-MFMA(B) in issue order)
#pragma unroll
    for (int qb = 0; qb < 4; ++qb) {
      float e0 = exp2f(sa[qb][0]);
      float e1 = exp2f(sa[qb][1]);
      float e2 = exp2f(sa[qb][2]);
      float e3 = exp2f(sa[qb][3]);
      lsum[qb] += (e0 + e1) + (e2 + e3);
      uint2 pk;
      pk.x = pack2bf(e0, e1);
      pk.y = pack2bf(e2, e3);
      *(uint2*)&Ps[(16 * qb + l16) * 136 + 16 * w + 4 * quad] = pk;
    }
#pragma unroll
    for (int qb = 0; qb < 4; ++qb) {
      float e0 = exp2f(sb[qb][0]);
      float e1 = exp2f(sb[qb][1]);
      float e2 = exp2f(sb[qb][2]);
      float e3 = exp2f(sb[qb][3]);
      lsum[qb] += (e0 + e1) + (e2 + e3);
      uint2 pk;
      pk.x = pack2bf(e0, e1);
      pk.y = pack2bf(e2, e3);
      *(uint2*)&Ps[(16 * qb + l16) * 136 + 64 + 16 * w + 4 * quad] = pk;
    }
    __syncthreads();

    // O^T += VT @ P^T over 128 keys
#pragma unroll
    for (int c = 0; c < 4; ++c)
#pragma unroll
      for (int qb = 0; qb < 4; ++qb) {
        bf16x8 bp = *(const bf16x8*)&Ps[(16 * qb + l16) * 136 + 32 * c + 8 * quad];
        oacc[qb] = __builtin_amdgcn_mfma_f32_16x16x32_bf16(av[c], bp, oacc[qb], 0, 0, 0);
      }
    __syncthreads();  // protect Ps against next iter's writes
  }

  // ---- softmax denominator: reduce over quad (keys) then waves ----
#pragma unroll
  for (int qb = 0; qb < 4; ++qb) {
    lsum[qb] += __shfl_xor(lsum[qb], 16, 64);
    lsum[qb] += __shfl_xor(lsum[qb], 32, 64);
  }
  if (lane < 16)
#pragma unroll
    for (int qb = 0; qb < 4; ++qb) Lred[w][qb * 16 + l16] = lsum[qb];
  __syncthreads();
  if (t < 64)
    Lred[0][t] = 1.0f / (Lred[0][t] + Lred[1][t] + Lred[2][t] + Lred[3][t]);
  __syncthreads();

  // ---- epilogue: oacc[qb][r] = O^T[d=16w+4quad+r][q=16qb+l16], packed store ----
  const int b = bh >> 4, h = bh & 15;
#pragma unroll
  for (int qb = 0; qb < 4; ++qb) {
    float li = Lred[0][16 * qb + l16];
    int s = qt * 64 + 16 * qb + l16;
    size_t base = (size_t)b * S_LEN * EMB + (size_t)s * EMB + h * 64 + 16 * w + 4 * quad;
    uint2 pk;
    pk.x = pack2bf(oacc[qb][0] * li, oacc[qb][1] * li);
    pk.y = pack2bf(oacc[qb][2] * li, oacc[qb][3] * li);
    *(uint2*)&AO[base] = pk;
  }
}

extern "C" void kernel_launch(void* const* d_in, const int* in_sizes, int n_in,
                              void* d_out, int out_size, void* d_ws, size_t ws_size,
                              hipStream_t stream) {
  (void)in_sizes; (void)n_in; (void)out_size; (void)ws_size;
  const float* x   = (const float*)d_in[0];
  const float* Wq  = (const float*)d_in[1];
  const float* bq  = (const float*)d_in[2];
  const float* Wk  = (const float*)d_in[3];
  const float* bk  = (const float*)d_in[4];
  const float* Wv  = (const float*)d_in[5];
  const float* bv  = (const float*)d_in[6];
  const float* Wfc = (const float*)d_in[7];
  const float* bfc = (const float*)d_in[8];
  float* out = (float*)d_out;

  unsigned short* xb   = (unsigned short*)d_ws;            // [4096][1024]
  unsigned short* Wqb  = xb + (size_t)4194304;             // Wq,Wk,Wv,Wfc contiguous
  unsigned short* Wfcb = Wqb + 3 * 1048576;
  unsigned short* Qhd  = Wfcb + 1048576;                   // [32][2048][64]
  unsigned short* Khd  = Qhd + 4194304;
  unsigned short* KTd  = Khd + 4194304;                    // [32][64][2048]
  unsigned short* VTd  = KTd + 4194304;                    // [32][64][2048]
  unsigned short* AOd  = VTd + 4194304;                    // [2][2048][1024]
  unsigned short* ginv = AOd + 4194304;                    // [32][64][64] bf16

  cast_kernel<<<4096, 256, 0, stream>>>(x, Wq, Wk, Wv, Wfc, xb);
  gemm_qkv<<<dim3(8, 32, 3), 256, 0, stream>>>(xb, Wqb, bq, bk, bv,
                                               Qhd, Khd, KTd, VTd);
  graminv_kernel<<<32, 256, 0, stream>>>(KTd, ginv);
  flash_mfma<<<1024, 256, 0, stream>>>(Qhd, Khd, VTd, ginv, AOd);
  gemm_fc<<<dim3(16, 32), 256, 0, stream>>>(AOd, Wfcb, bfc, out);
}

// Round 8
// 280.091 us; speedup vs baseline: 1.0904x; 1.0904x over previous
//
#include <hip/hip_runtime.h>
#include <cstddef>
#include <cstdint>

#define S_LEN 2048
#define NHEAD 16
#define HDIM  64
#define EMB   1024
#define MROWS 4096

typedef short bf16x8 __attribute__((ext_vector_type(8)));
typedef float f32x4 __attribute__((ext_vector_type(4)));

// round-to-nearest fp32->bf16: 2 VALU ops
__device__ __forceinline__ unsigned short f2bf(float f) {
  union { float f; unsigned u; } v; v.f = f;
  return (unsigned short)((v.u + 0x8000u) >> 16);
}
__device__ __forceinline__ unsigned pack2bf(float a, float b) {
  union { float f; unsigned u; } x, y; x.f = a; y.f = b;
  return ((x.u + 0x8000u) >> 16) | ((y.u + 0x8000u) & 0xFFFF0000u);
}

__device__ __forceinline__ f32x4 fzero() {
  f32x4 z = {0.0f, 0.0f, 0.0f, 0.0f};
  return z;
}

// Cast x (4M), Wq,Wk,Wv,Wfc (1M each) fp32 -> bf16, contiguous dst.
__global__ __launch_bounds__(256) void cast_kernel(
    const float* __restrict__ x, const float* __restrict__ Wq,
    const float* __restrict__ Wk, const float* __restrict__ Wv,
    const float* __restrict__ Wfc, unsigned short* __restrict__ dst)
{
  size_t idx8 = (size_t)(blockIdx.x * 256 + threadIdx.x) * 8;
  unsigned seg = (unsigned)(idx8 >> 20);
  const float* src;
  size_t off;
  if (seg < 4) { src = x; off = idx8; }
  else {
    const float* w4[4] = {Wq, Wk, Wv, Wfc};
    src = w4[seg - 4];
    off = idx8 & 0xFFFFFu;
  }
  float4 a = *(const float4*)&src[off];
  float4 b = *(const float4*)&src[off + 4];
  uint4 p;
  p.x = pack2bf(a.x, a.y);
  p.y = pack2bf(a.z, a.w);
  p.z = pack2bf(b.x, b.y);
  p.w = pack2bf(b.z, b.w);
  *(uint4*)&dst[idx8] = p;
}

// QKV fused (register-prefetch staging). z selects weight/bias/output.
// z=0: Qhd [bh][s][d]; z=1: Khd [bh][s][d]; z=2: VTd [bh][d][s] via LDS transpose.
__global__ __launch_bounds__(256) void gemm_qkv(
    const unsigned short* __restrict__ A, const unsigned short* __restrict__ Wall,
    const float* __restrict__ bq, const float* __restrict__ bk,
    const float* __restrict__ bv, unsigned short* __restrict__ Qhd,
    unsigned short* __restrict__ Khd, unsigned short* __restrict__ VTd)
{
  __shared__ short As[128][40];
  __shared__ short Bs[128][40];
  __shared__ short Ts[64][136];   // z==2 transpose staging
  const int z = blockIdx.z;
  const unsigned short* B = Wall + (size_t)z * 1048576;
  const float* bias = (z == 0) ? bq : (z == 1) ? bk : bv;
  const int K = EMB;
  const int t = threadIdx.x;
  const int lane = t & 63, w = t >> 6;
  const int quad = lane >> 4, l16 = lane & 15;
  const int wr = w >> 1, wc = w & 1;
  const int m0 = blockIdx.y * 128, n0 = blockIdx.x * 128;
  const int sr = t >> 2, sk = (t & 3) * 8;

  f32x4 acc[4][4];
#pragma unroll
  for (int i = 0; i < 4; ++i)
#pragma unroll
    for (int j = 0; j < 4; ++j) acc[i][j] = fzero();

  float4 pa0 = *(const float4*)&A[(size_t)(m0 + sr) * K + sk];
  float4 pa1 = *(const float4*)&A[(size_t)(m0 + 64 + sr) * K + sk];
  float4 pb0 = *(const float4*)&B[(size_t)(n0 + sr) * K + sk];
  float4 pb1 = *(const float4*)&B[(size_t)(n0 + 64 + sr) * K + sk];

  for (int k0 = 0; k0 < K; k0 += 32) {
    __syncthreads();
    *(float4*)&As[sr][sk] = pa0;
    *(float4*)&As[64 + sr][sk] = pa1;
    *(float4*)&Bs[sr][sk] = pb0;
    *(float4*)&Bs[64 + sr][sk] = pb1;
    __syncthreads();
    if (k0 + 32 < K) {
      pa0 = *(const float4*)&A[(size_t)(m0 + sr) * K + k0 + 32 + sk];
      pa1 = *(const float4*)&A[(size_t)(m0 + 64 + sr) * K + k0 + 32 + sk];
      pb0 = *(const float4*)&B[(size_t)(n0 + sr) * K + k0 + 32 + sk];
      pb1 = *(const float4*)&B[(size_t)(n0 + 64 + sr) * K + k0 + 32 + sk];
    }
    bf16x8 af[4], bfr[4];
#pragma unroll
    for (int i = 0; i < 4; ++i)
      af[i] = *(const bf16x8*)&As[64 * wr + 16 * i + l16][quad * 8];
#pragma unroll
    for (int j = 0; j < 4; ++j)
      bfr[j] = *(const bf16x8*)&Bs[64 * wc + 16 * j + l16][quad * 8];
#pragma unroll
    for (int i = 0; i < 4; ++i)
#pragma unroll
      for (int j = 0; j < 4; ++j)
        acc[i][j] = __builtin_amdgcn_mfma_f32_16x16x32_bf16(af[i], bfr[j], acc[i][j], 0, 0, 0);
  }

  if (z < 2) {
    unsigned short* Yh = (z == 0) ? Qhd : Khd;
#pragma unroll
    for (int i = 0; i < 4; ++i) {
      int mb = m0 + 64 * wr + 16 * i + quad * 4;
#pragma unroll
      for (int j = 0; j < 4; ++j) {
        int n = n0 + 64 * wc + 16 * j + l16;
        float bvv = bias[n];
        int h = n >> 6, d = n & 63;
#pragma unroll
        for (int r = 0; r < 4; ++r) {
          int m = mb + r;
          int b = m >> 11, s = m & 2047;
          Yh[((size_t)(b * NHEAD + h)) * 131072 + (size_t)s * 64 + d] =
              f2bf(acc[i][j][r] + bvv);
        }
      }
    }
  } else {
    // V: transpose C through LDS, one 64-col (one-head) half at a time,
    // then write VT rows with 64B-contiguous stores.
#pragma unroll
    for (int hh = 0; hh < 2; ++hh) {
      __syncthreads();
      if (wc == hh) {
#pragma unroll
        for (int i = 0; i < 4; ++i)
#pragma unroll
          for (int j = 0; j < 4; ++j) {
            int n = n0 + 64 * wc + 16 * j + l16;
            float bvv = bias[n];
            int dl = 16 * j + l16;
            uint2 pk;
            pk.x = pack2bf(acc[i][j][0] + bvv, acc[i][j][1] + bvv);
            pk.y = pack2bf(acc[i][j][2] + bvv, acc[i][j][3] + bvv);
            *(uint2*)&Ts[dl][64 * wr + 16 * i + 4 * quad] = pk;
          }
      }
      __syncthreads();
      int dl = t >> 2, s0 = (t & 3) * 32;
      int n = n0 + 64 * hh + dl;
      int h = n >> 6, d = n & 63;
      int b = m0 >> 11, sbase = (m0 & 2047) + s0;
      unsigned short* dst =
          &VTd[((size_t)(b * NHEAD + h)) * 131072 + (size_t)d * S_LEN + sbase];
#pragma unroll
      for (int k2 = 0; k2 < 4; ++k2)
        *(uint4*)&dst[8 * k2] = *(const uint4*)&Ts[dl][s0 + 8 * k2];
    }
  }
}

// Final: out = AO @ Wfc^T + bfc, fp32 out [M][N]. 128x64 tiles -> 512 blocks.
__global__ __launch_bounds__(256) void gemm_fc(
    const unsigned short* __restrict__ A, const unsigned short* __restrict__ B,
    const float* __restrict__ bias, float* __restrict__ Yf)
{
  __shared__ short As[128][40];
  __shared__ short Bs[64][40];
  const int K = EMB, N = EMB;
  const int t = threadIdx.x;
  const int lane = t & 63, w = t >> 6;
  const int quad = lane >> 4, l16 = lane & 15;
  const int wr = w >> 1, wc = w & 1;
  const int m0 = blockIdx.y * 128, n0 = blockIdx.x * 64;
  const int sr = t >> 2, sk = (t & 3) * 8;

  f32x4 acc[4][2];
#pragma unroll
  for (int i = 0; i < 4; ++i)
#pragma unroll
    for (int j = 0; j < 2; ++j) acc[i][j] = fzero();

  float4 pa0 = *(const float4*)&A[(size_t)(m0 + sr) * K + sk];
  float4 pa1 = *(const float4*)&A[(size_t)(m0 + 64 + sr) * K + sk];
  float4 pb0 = *(const float4*)&B[(size_t)(n0 + sr) * K + sk];

  for (int k0 = 0; k0 < K; k0 += 32) {
    __syncthreads();
    *(float4*)&As[sr][sk] = pa0;
    *(float4*)&As[64 + sr][sk] = pa1;
    if (sr < 64) *(float4*)&Bs[sr][sk] = pb0;
    __syncthreads();
    if (k0 + 32 < K) {
      pa0 = *(const float4*)&A[(size_t)(m0 + sr) * K + k0 + 32 + sk];
      pa1 = *(const float4*)&A[(size_t)(m0 + 64 + sr) * K + k0 + 32 + sk];
      pb0 = *(const float4*)&B[(size_t)(n0 + sr) * K + k0 + 32 + sk];
    }
    bf16x8 af[4], bfr[2];
#pragma unroll
    for (int i = 0; i < 4; ++i)
      af[i] = *(const bf16x8*)&As[64 * wr + 16 * i + l16][quad * 8];
#pragma unroll
    for (int j = 0; j < 2; ++j)
      bfr[j] = *(const bf16x8*)&Bs[32 * wc + 16 * j + l16][quad * 8];
#pragma unroll
    for (int i = 0; i < 4; ++i)
#pragma unroll
      for (int j = 0; j < 2; ++j)
        acc[i][j] = __builtin_amdgcn_mfma_f32_16x16x32_bf16(af[i], bfr[j], acc[i][j], 0, 0, 0);
  }

#pragma unroll
  for (int i = 0; i < 4; ++i) {
    int mb = m0 + 64 * wr + 16 * i + quad * 4;
#pragma unroll
    for (int j = 0; j < 2; ++j) {
      int n = n0 + 32 * wc + 16 * j + l16;
      float bvv = bias[n];
#pragma unroll
      for (int r = 0; r < 4; ++r)
        Yf[(size_t)(mb + r) * N + n] = acc[i][j][r] + bvv;
    }
  }
}

// Partial gram from Khd [bh][s][d] (coalesced reads, in-LDS transpose).
// block bx -> bh = bx>>2, part = bx&3 (512-seq chunk).
__global__ __launch_bounds__(256) void gram_mfma(
    const unsigned short* __restrict__ Khd, float* __restrict__ gram_p)
{
  __shared__ short KTs[64][136];
  const int t = threadIdx.x;
  const int lane = t & 63, w = t >> 6;
  const int quad = lane >> 4, l16 = lane & 15;
  const int bh = blockIdx.x >> 2, part = blockIdx.x & 3;
  const unsigned short* Kb = Khd + (size_t)bh * 131072 + (size_t)part * 512 * 64;

  f32x4 gacc[4];
#pragma unroll
  for (int j = 0; j < 4; ++j) gacc[j] = fzero();

  const int r8 = t >> 1;         // s-row 0..127
  const int c8 = (t & 1) * 32;   // d offset 0/32
  for (int st = 0; st < 4; ++st) {
    float4 kv[4];
#pragma unroll
    for (int i = 0; i < 4; ++i)
      kv[i] = *(const float4*)&Kb[(size_t)(st * 128 + r8) * 64 + c8 + 8 * i];
    __syncthreads();
#pragma unroll
    for (int i = 0; i < 4; ++i) {
      union { float4 f; unsigned short h[8]; } u;
      u.f = kv[i];
#pragma unroll
      for (int jj = 0; jj < 8; ++jj)
        KTs[c8 + 8 * i + jj][r8] = (short)u.h[jj];
    }
    __syncthreads();
#pragma unroll
    for (int c = 0; c < 4; ++c) {
      bf16x8 ai = *(const bf16x8*)&KTs[16 * w + l16][32 * c + quad * 8];
#pragma unroll
      for (int jb = 0; jb < 4; ++jb) {
        bf16x8 bj = *(const bf16x8*)&KTs[16 * jb + l16][32 * c + quad * 8];
        gacc[jb] = __builtin_amdgcn_mfma_f32_16x16x32_bf16(ai, bj, gacc[jb], 0, 0, 0);
      }
    }
  }
#pragma unroll
  for (int jb = 0; jb < 4; ++jb)
#pragma unroll
    for (int r = 0; r < 4; ++r)
      gram_p[(size_t)blockIdx.x * 4096 +
             (size_t)(16 * w + quad * 4 + r) * 64 + 16 * jb + l16] = gacc[jb][r];
}

// In-place Gauss-Jordan inverse, 64x64 SPD (diag-dominant, no pivoting).
// Sums 4 gram partials on load; one barrier per pivot. bf16 out.
__global__ __launch_bounds__(256) void inv_kernel(
    const float* __restrict__ gram_p, unsigned short* __restrict__ ginv)
{
  __shared__ float As[64][68];
  __shared__ float prow[2][64];
  __shared__ float fcol[2][64];
  const int bh = blockIdx.x;
  const int t = threadIdx.x;
  const int r = t >> 2;
  const int c0 = (t & 3) * 16;
  const float* G = gram_p + (size_t)bh * 4 * 4096;

  float4 g[4];
#pragma unroll
  for (int jj = 0; jj < 4; ++jj) {
    int off = r * 64 + c0 + 4 * jj;
    float4 s0 = *(const float4*)&G[off];
    float4 s1 = *(const float4*)&G[4096 + off];
    float4 s2 = *(const float4*)&G[8192 + off];
    float4 s3 = *(const float4*)&G[12288 + off];
    g[jj].x = (s0.x + s1.x) + (s2.x + s3.x);
    g[jj].y = (s0.y + s1.y) + (s2.y + s3.y);
    g[jj].z = (s0.z + s1.z) + (s2.z + s3.z);
    g[jj].w = (s0.w + s1.w) + (s2.w + s3.w);
    *(float4*)&As[r][c0 + 4 * jj] = g[jj];
  }
  if (c0 == 0) fcol[0][r] = g[0].x;
  if (r == 0) {
#pragma unroll
    for (int jj = 0; jj < 4; ++jj) *(float4*)&prow[0][c0 + 4 * jj] = g[jj];
  }
  __syncthreads();

  for (int k = 0; k < 64; ++k) {
    const int kb = k & 1;
    const float f = fcol[kb][r];
    const float ip = 1.0f / fcol[kb][k];
    const float fi = f * ip;
    const bool pr = (r == k);
    float4 nv[4];
#pragma unroll
    for (int jj = 0; jj < 4; ++jj) {
      float4 a = *(const float4*)&As[r][c0 + 4 * jj];
      float4 p = *(const float4*)&prow[kb][c0 + 4 * jj];
      float4 o;
      if (pr) {
        o.x = p.x * ip; o.y = p.y * ip; o.z = p.z * ip; o.w = p.w * ip;
      } else {
        o.x = fmaf(-fi, p.x, a.x); o.y = fmaf(-fi, p.y, a.y);
        o.z = fmaf(-fi, p.z, a.z); o.w = fmaf(-fi, p.w, a.w);
      }
      const int cb = c0 + 4 * jj;
      const float kv = pr ? ip : -fi;
      if (cb == k) o.x = kv;
      if (cb + 1 == k) o.y = kv;
      if (cb + 2 == k) o.z = kv;
      if (cb + 3 == k) o.w = kv;
      *(float4*)&As[r][c0 + 4 * jj] = o;
      nv[jj] = o;
    }
    if (k < 63) {
      const int nk = k + 1, nb = nk & 1;
      if (nk >= c0 && nk < c0 + 16) fcol[nb][r] = As[r][nk];
      if (r == nk) {
#pragma unroll
        for (int jj = 0; jj < 4; ++jj) *(float4*)&prow[nb][c0 + 4 * jj] = nv[jj];
      }
    }
    __syncthreads();
  }

  unsigned short* O = ginv + (size_t)bh * 4096;
#pragma unroll
  for (int jj = 0; jj < 4; ++jj) {
    float4 v = *(const float4*)&As[r][c0 + 4 * jj];
    uint2 pk;
    pk.x = pack2bf(v.x, v.y);
    pk.y = pack2bf(v.z, v.w);
    *(uint2*)&O[r * 64 + c0 + 4 * jj] = pk;
  }
}

// Fused flash (R6 structure): Qp register-resident B-frags, V early-issue,
// wrapped K prefetch, double-buffered Ps, 1 barrier/iter, XCD swizzle.
// New: coalesced AO epilogue via LDS transpose (reuses Qps).
__global__ __launch_bounds__(256, 4) void flash_mfma(
    const unsigned short* __restrict__ Qh, const unsigned short* __restrict__ Kh,
    const unsigned short* __restrict__ VTh, const unsigned short* __restrict__ Ginv,
    unsigned short* __restrict__ AO)
{
  __shared__ short Qps[64 * 72];      // [q][d], stride 72
  __shared__ short Ps[2][64 * 72];    // [q][key], stride 72, double-buffered
  __shared__ float Lred[4][64];
  const int t = threadIdx.x;
  const int lane = t & 63, w = t >> 6;
  const int quad = lane >> 4, l16 = lane & 15;
  const int id = blockIdx.x;
  const int qt = (id >> 3) & 31;
  const int bh = ((id >> 8) << 3) | (id & 7);
  const unsigned short* Qb = Qh + (size_t)bh * 131072;
  const unsigned short* Kb = Kh + (size_t)bh * 131072;
  const unsigned short* Vb = VTh + (size_t)bh * 131072;
  const unsigned short* Gb = Ginv + (size_t)bh * 4096;

  // ---- phase 0: Qp = (Q @ Ginv) * log2(e)/32 -> Qps; prefetch K(0) ----
  bf16x8 ak[2];
#pragma unroll
  for (int c = 0; c < 2; ++c)
    ak[c] = *(const bf16x8*)&Kb[(size_t)(16 * w + l16) * 64 + 32 * c + 8 * quad];
  {
    bf16x8 aq[2];
#pragma unroll
    for (int c = 0; c < 2; ++c)
      aq[c] = *(const bf16x8*)&Qb[(size_t)(qt * 64 + 16 * w + l16) * 64 + 32 * c + 8 * quad];
    f32x4 qacc[4];
#pragma unroll
    for (int nb = 0; nb < 4; ++nb) qacc[nb] = fzero();
#pragma unroll
    for (int c = 0; c < 2; ++c) {
#pragma unroll
      for (int nb = 0; nb < 4; ++nb) {
        // B[k=d][n=d'] = Ginv[d][d'] = Ginv[d'][d] (symmetric) -> row load
        bf16x8 bg = *(const bf16x8*)&Gb[(size_t)(16 * nb + l16) * 64 + 32 * c + 8 * quad];
        qacc[nb] = __builtin_amdgcn_mfma_f32_16x16x32_bf16(aq[c], bg, qacc[nb], 0, 0, 0);
      }
    }
    const float cs = 0.04508422f;  // log2(e)/32
#pragma unroll
    for (int nb = 0; nb < 4; ++nb)
#pragma unroll
      for (int r = 0; r < 4; ++r)
        Qps[(16 * w + 4 * quad + r) * 72 + 16 * nb + l16] =
            (short)f2bf(qacc[nb][r] * cs);
  }
  __syncthreads();

  // Qp^T B-frags: register-resident, loop-invariant
  bf16x8 bqf[2][4];
#pragma unroll
  for (int c = 0; c < 2; ++c)
#pragma unroll
    for (int qb = 0; qb < 4; ++qb)
      bqf[c][qb] = *(const bf16x8*)&Qps[(16 * qb + l16) * 72 + 32 * c + 8 * quad];

  f32x4 oacc[4];
#pragma unroll
  for (int qb = 0; qb < 4; ++qb) oacc[qb] = fzero();
  float lsum[4] = {0.0f, 0.0f, 0.0f, 0.0f};

  for (int kt = 0; kt < 32; ++kt) {
    // issue V(kt) now; consumed after barrier (S-MFMA + exp hide the latency)
    bf16x8 av[2];
#pragma unroll
    for (int c = 0; c < 2; ++c)
      av[c] = *(const bf16x8*)&Vb[(size_t)(16 * w + l16) * S_LEN + kt * 64 + 32 * c + 8 * quad];

    // S^T = K @ Qp^T : wave w owns keys [16w,16w+16) of this 64-key tile
    f32x4 sacc[4];
#pragma unroll
    for (int qb = 0; qb < 4; ++qb) sacc[qb] = fzero();
#pragma unroll
    for (int c = 0; c < 2; ++c)
#pragma unroll
      for (int qb = 0; qb < 4; ++qb)
        sacc[qb] = __builtin_amdgcn_mfma_f32_16x16x32_bf16(ak[c], bqf[c][qb], sacc[qb], 0, 0, 0);

    // prefetch K(kt+1), wrapped (unconditional -> stays in VGPRs)
    const int nk = (kt + 1) & 31;
#pragma unroll
    for (int c = 0; c < 2; ++c)
      ak[c] = *(const bf16x8*)&Kb[(size_t)(nk * 64 + 16 * w + l16) * 64 + 32 * c + 8 * quad];

    // P = 2^S -> Ps[buf]
    short* Pbuf = &Ps[kt & 1][0];
#pragma unroll
    for (int qb = 0; qb < 4; ++qb) {
      float e0 = exp2f(sacc[qb][0]);
      float e1 = exp2f(sacc[qb][1]);
      float e2 = exp2f(sacc[qb][2]);
      float e3 = exp2f(sacc[qb][3]);
      lsum[qb] += (e0 + e1) + (e2 + e3);
      uint2 pk;
      pk.x = pack2bf(e0, e1);
      pk.y = pack2bf(e2, e3);
      *(uint2*)&Pbuf[(16 * qb + l16) * 72 + 16 * w + 4 * quad] = pk;
    }
    __syncthreads();

    // O^T += VT @ P^T : wave w owns d-rows [16w,16w+16)
#pragma unroll
    for (int c = 0; c < 2; ++c)
#pragma unroll
      for (int qb = 0; qb < 4; ++qb) {
        bf16x8 bp = *(const bf16x8*)&Pbuf[(16 * qb + l16) * 72 + 32 * c + 8 * quad];
        oacc[qb] = __builtin_amdgcn_mfma_f32_16x16x32_bf16(av[c], bp, oacc[qb], 0, 0, 0);
      }
    // no trailing barrier: next write targets the other Ps buffer
  }

  // ---- softmax denominator: reduce over quad (keys) then waves ----
#pragma unroll
  for (int qb = 0; qb < 4; ++qb) {
    lsum[qb] += __shfl_xor(lsum[qb], 16, 64);
    lsum[qb] += __shfl_xor(lsum[qb], 32, 64);
  }
  if (lane < 16)
#pragma unroll
    for (int qb = 0; qb < 4; ++qb) Lred[w][qb * 16 + l16] = lsum[qb];
  __syncthreads();
  if (t < 64)
    Lred[0][t] = 1.0f / (Lred[0][t] + Lred[1][t] + Lred[2][t] + Lred[3][t]);
  __syncthreads();

  // ---- epilogue: stage O[q][d] into Qps (scaled), then coalesced AO rows ----
#pragma unroll
  for (int qb = 0; qb < 4; ++qb) {
    float li = Lred[0][16 * qb + l16];
    uint2 pk;
    pk.x = pack2bf(oacc[qb][0] * li, oacc[qb][1] * li);
    pk.y = pack2bf(oacc[qb][2] * li, oacc[qb][3] * li);
    *(uint2*)&Qps[(16 * qb + l16) * 72 + 16 * w + 4 * quad] = pk;
  }
  __syncthreads();
  {
    const int b = bh >> 4, h = bh & 15;
    int q = t >> 2, d0 = (t & 3) * 16;
    uint4 v0 = *(const uint4*)&Qps[q * 72 + d0];
    uint4 v1 = *(const uint4*)&Qps[q * 72 + d0 + 8];
    size_t base = (size_t)b * S_LEN * EMB + (size_t)(qt * 64 + q) * EMB + h * 64 + d0;
    *(uint4*)&AO[base] = v0;
    *(uint4*)&AO[base + 8] = v1;
  }
}

extern "C" void kernel_launch(void* const* d_in, const int* in_sizes, int n_in,
                              void* d_out, int out_size, void* d_ws, size_t ws_size,
                              hipStream_t stream) {
  (void)in_sizes; (void)n_in; (void)out_size; (void)ws_size;
  const float* x   = (const float*)d_in[0];
  const float* Wq  = (const float*)d_in[1];
  const float* bq  = (const float*)d_in[2];
  const float* Wk  = (const float*)d_in[3];
  const float* bk  = (const float*)d_in[4];
  const float* Wv  = (const float*)d_in[5];
  const float* bv  = (const float*)d_in[6];
  const float* Wfc = (const float*)d_in[7];
  const float* bfc = (const float*)d_in[8];
  float* out = (float*)d_out;

  unsigned short* xb   = (unsigned short*)d_ws;            // [4096][1024]
  unsigned short* Wqb  = xb + (size_t)4194304;             // Wq,Wk,Wv,Wfc contiguous
  unsigned short* Wfcb = Wqb + 3 * 1048576;
  unsigned short* Qhd  = Wfcb + 1048576;                   // [32][2048][64]
  unsigned short* Khd  = Qhd + 4194304;
  unsigned short* VTd  = Khd + 4194304;                    // [32][64][2048]
  unsigned short* AOd  = VTd + 4194304;                    // [2][2048][1024]
  float* gram_p        = (float*)(AOd + 4194304);          // [128][64][64] f32
  unsigned short* ginv = (unsigned short*)(gram_p + 524288); // [32][64][64] bf16

  cast_kernel<<<4096, 256, 0, stream>>>(x, Wq, Wk, Wv, Wfc, xb);
  gemm_qkv<<<dim3(8, 32, 3), 256, 0, stream>>>(xb, Wqb, bq, bk, bv,
                                               Qhd, Khd, VTd);
  gram_mfma<<<128, 256, 0, stream>>>(Khd, gram_p);
  inv_kernel<<<32, 256, 0, stream>>>(gram_p, ginv);
  flash_mfma<<<1024, 256, 0, stream>>>(Qhd, Khd, VTd, ginv, AOd);
  gemm_fc<<<dim3(16, 32), 256, 0, stream>>>(AOd, Wfcb, bfc, out);
}